// Round 11
// baseline (253.182 us; speedup 1.0000x reference)
//
#include <hip/hip_runtime.h>
#include <hip/hip_bf16.h>
#include <stddef.h>

// Problem dims
#define BB 64
#define TTOT 64
#define EE 64
#define HH 128
#define G4 512          // 4*H
#define VIN 256
#define VOUT 32000

typedef __attribute__((ext_vector_type(8))) short bf16x8;
typedef __attribute__((ext_vector_type(4))) float f32x4;
typedef __attribute__((ext_vector_type(2))) float f32x2;

__device__ __forceinline__ unsigned short f2bf(float x) {
    unsigned int u = __float_as_uint(x);
    unsigned int r = (u + 0x7fffu + ((u >> 16) & 1u)) >> 16;
    return (unsigned short)r;
}

__device__ __forceinline__ float fsig(float x) {
    return 1.f / (1.f + __expf(-x));
}
__device__ __forceinline__ float ftanh(float x) {
    return 1.f - 2.f / (__expf(2.f * x) + 1.f);
}

// packed fp32 FMA: d.lo = a.lo*b.lo + d.lo ; d.hi = a.hi*b.hi + d.hi
__device__ __forceinline__ f32x2 pkfma(f32x2 a, f32x2 b, f32x2 d) {
    asm("v_pk_fma_f32 %0, %1, %2, %0" : "+v"(d) : "v"(a), "v"(b));
    return d;
}

// quad (4-lane) butterfly sum via DPP quad_perm — pure VALU, no DS ops.
__device__ __forceinline__ float quad_sum(float v) {
    v += __int_as_float(__builtin_amdgcn_mov_dpp(__float_as_int(v), 0xB1, 0xF, 0xF, true));  // xor 1
    v += __int_as_float(__builtin_amdgcn_mov_dpp(__float_as_int(v), 0x4E, 0xF, 0xF, true));  // xor 2
    return v;
}

// LDS h layout: pad 8 dwords every 32 so the four 32-float quarters start in
// different bank groups: idx(u) = u + (u>>5)*8  (quarter p base = p*40 dwords)
__device__ __forceinline__ int hidx(int u) { return u + (u >> 5) * 8; }
#define HPAD 152

// ---------------- prep kernel: enc_table (blocks 0..255) + xg_dec (blocks 256..507) ----------------
__global__ __launch_bounds__(512) void prep_k(const float* __restrict__ enc_emb,
                                              const float* __restrict__ eWih,
                                              const float* __restrict__ ebih,
                                              float* __restrict__ table,
                                              const int* __restrict__ tgt,
                                              const float* __restrict__ dec_emb,
                                              const float* __restrict__ dWih,
                                              const float* __restrict__ dbih,
                                              float* __restrict__ xg) {
    __shared__ __align__(16) float x[16][EE];
    int g = threadIdx.x;
    if (blockIdx.x < 256) {
        int v = blockIdx.x;
        if (g < EE) x[0][g] = (v == 0) ? 0.f : enc_emb[(size_t)v * EE + g];
        __syncthreads();
        float acc = ebih[g];
        const float* wr = eWih + (size_t)g * EE;
#pragma unroll
        for (int e = 0; e < EE; e += 4) {
            float4 w4 = *(const float4*)(wr + e);
            float4 x4 = *(const float4*)(&x[0][e]);
            acc = fmaf(x4.x, w4.x, acc);
            acc = fmaf(x4.y, w4.y, acc);
            acc = fmaf(x4.z, w4.z, acc);
            acc = fmaf(x4.w, w4.w, acc);
        }
        table[(size_t)v * G4 + g] = acc;
    } else {
        int p0 = (blockIdx.x - 256) * 16;  // pair index = t*64 + b, t in [0,63)
        {
            int e = g & 63;
#pragma unroll
            for (int half = 0; half < 2; ++half) {
                int pr = (g >> 6) + half * 8;
                int pair = p0 + pr;
                int t = pair >> 6, b = pair & 63;
                int tok = tgt[b * TTOT + t];
                x[pr][e] = (tok == 0) ? 0.f : dec_emb[(size_t)tok * EE + e];
            }
        }
        __syncthreads();
        float bi = dbih[g];
        float acc[16];
#pragma unroll
        for (int pr = 0; pr < 16; ++pr) acc[pr] = bi;
        const float* wr = dWih + (size_t)g * EE;
#pragma unroll
        for (int e = 0; e < EE; e += 4) {
            float4 w4 = *(const float4*)(wr + e);
#pragma unroll
            for (int pr = 0; pr < 16; ++pr) {
                float4 x4 = *(const float4*)(&x[pr][e]);
                acc[pr] = fmaf(x4.x, w4.x, acc[pr]);
                acc[pr] = fmaf(x4.y, w4.y, acc[pr]);
                acc[pr] = fmaf(x4.z, w4.z, acc[pr]);
                acc[pr] = fmaf(x4.w, w4.w, acc[pr]);
            }
        }
#pragma unroll
        for (int pr = 0; pr < 16; ++pr)
            xg[(size_t)(p0 + pr) * G4 + g] = acc[pr];
    }
}

// ---------------- fused encoder+decoder LSTM (blocks 0..63) + fc_W bf16 convert (blocks 64..575) ----------------
__global__ __launch_bounds__(512) void lstm_k(const float* __restrict__ table,
                                              const int* __restrict__ src,
                                              const float* __restrict__ eWhh,
                                              const float* __restrict__ ebhh,
                                              const float* __restrict__ xg,
                                              const float* __restrict__ dWhh,
                                              const float* __restrict__ dbhh,
                                              unsigned short* __restrict__ hs,
                                              const float* __restrict__ fcW,
                                              unsigned short* __restrict__ fwb) {
    if (blockIdx.x >= BB) {
        // fc_W fp32 -> bf16, grid-stride over float4 items
        int i0 = (blockIdx.x - BB) * 512 + threadIdx.x;
        const int n4 = VOUT * HH / 4;       // 1,024,000
        const int stride = 512 * 512;       // 262,144
#pragma unroll 1
        for (int i = i0; i < n4; i += stride) {
            float4 v = *(const float4*)(fcW + (size_t)i * 4);
            ushort4 o;
            o.x = f2bf(v.x); o.y = f2bf(v.y); o.z = f2bf(v.z); o.w = f2bf(v.w);
            *(ushort4*)(fwb + (size_t)i * 4) = o;
        }
        return;
    }

    int b = blockIdx.x;
    int tid = threadIdx.x;
    int u = tid >> 2, p = tid & 3;
    __shared__ __align__(16) float hbuf[2][HPAD];
    __shared__ int toks[TTOT];

    // encoder weights as f32x2 pairs: w2[q][j] = Whh[q*128+u][p*32 + 2j .. 2j+1]
    f32x2 w2[4][16];
#pragma unroll
    for (int q = 0; q < 4; ++q) {
        const float* wr = eWhh + (size_t)(q * HH + u) * HH + p * 32;
#pragma unroll
        for (int kk = 0; kk < 32; kk += 4) {
            float4 t4 = *(const float4*)(wr + kk);
            w2[q][kk >> 1] = (f32x2){t4.x, t4.y};
            w2[q][(kk >> 1) + 1] = (f32x2){t4.z, t4.w};
        }
    }
    if (tid < TTOT) toks[tid] = src[b * TTOT + tid];
    if (p == 0) {
        hbuf[0][hidx(u)] = 0.f;
        hs[((size_t)b << 13) + u] = 0;  // out-row 0 operand = zeros
    }
    float bb = ebhh[p * HH + u];
    float c = 0.f;
    __syncthreads();

    float xv = table[(size_t)toks[0] * G4 + p * HH + u];

    // ---- encoder: 64 steps ----
#pragma unroll 1
    for (int t = 0; t < TTOT; ++t) {
        float xn = (t + 1 < TTOT) ? table[(size_t)toks[t + 1] * G4 + p * HH + u] : 0.f;
        const float* hq = &hbuf[t & 1][p * 40];
        float4 h4[8];
#pragma unroll
        for (int j = 0; j < 8; ++j) h4[j] = *(const float4*)(hq + j * 4);

        f32x2 a0 = (f32x2){0.f, 0.f}, a1 = a0, a2 = a0, a3 = a0;
#pragma unroll
        for (int j = 0; j < 8; ++j) {
            float4 h = h4[j];
            f32x2 hlo = (f32x2){h.x, h.y};
            f32x2 hhi = (f32x2){h.z, h.w};
            a0 = pkfma(hlo, w2[0][2 * j], a0); a0 = pkfma(hhi, w2[0][2 * j + 1], a0);
            a1 = pkfma(hlo, w2[1][2 * j], a1); a1 = pkfma(hhi, w2[1][2 * j + 1], a1);
            a2 = pkfma(hlo, w2[2][2 * j], a2); a2 = pkfma(hhi, w2[2][2 * j + 1], a2);
            a3 = pkfma(hlo, w2[3][2 * j], a3); a3 = pkfma(hhi, w2[3][2 * j + 1], a3);
        }
        float xb = xv + bb;
        float v0 = a0[0] + a0[1] + (p == 0 ? xb : 0.f);
        float v1 = a1[0] + a1[1] + (p == 1 ? xb : 0.f);
        float v2 = a2[0] + a2[1] + (p == 2 ? xb : 0.f);
        float v3 = a3[0] + a3[1] + (p == 3 ? xb : 0.f);
        v0 = quad_sum(v0); v1 = quad_sum(v1); v2 = quad_sum(v2); v3 = quad_sum(v3);

        float fi = fsig(v0), ff = fsig(v1), fg = ftanh(v2), fo = fsig(v3);
        c = ff * c + fi * fg;
        float hn = fo * ftanh(c);
        if (p == 0) hbuf[(t + 1) & 1][hidx(u)] = hn;
        __syncthreads();
        xv = xn;
    }

    // ---- switch to decoder weights; h/c stay ----
#pragma unroll
    for (int q = 0; q < 4; ++q) {
        const float* wr = dWhh + (size_t)(q * HH + u) * HH + p * 32;
#pragma unroll
        for (int kk = 0; kk < 32; kk += 4) {
            float4 t4 = *(const float4*)(wr + kk);
            w2[q][kk >> 1] = (f32x2){t4.x, t4.y};
            w2[q][(kk >> 1) + 1] = (f32x2){t4.z, t4.w};
        }
    }
    bb = dbhh[p * HH + u];
    float xv2 = xg[(size_t)b * G4 + p * HH + u];  // t=0 (pair = 0*64 + b)

    // ---- decoder: 63 steps; enc ended with h in hbuf[0] ----
#pragma unroll 1
    for (int t = 0; t < TTOT - 1; ++t) {
        float xn = (t + 1 < TTOT - 1) ? xg[((size_t)(t + 1) * BB + b) * G4 + p * HH + u] : 0.f;
        const float* hq = &hbuf[t & 1][p * 40];
        float4 h4[8];
#pragma unroll
        for (int j = 0; j < 8; ++j) h4[j] = *(const float4*)(hq + j * 4);

        f32x2 a0 = (f32x2){0.f, 0.f}, a1 = a0, a2 = a0, a3 = a0;
#pragma unroll
        for (int j = 0; j < 8; ++j) {
            float4 h = h4[j];
            f32x2 hlo = (f32x2){h.x, h.y};
            f32x2 hhi = (f32x2){h.z, h.w};
            a0 = pkfma(hlo, w2[0][2 * j], a0); a0 = pkfma(hhi, w2[0][2 * j + 1], a0);
            a1 = pkfma(hlo, w2[1][2 * j], a1); a1 = pkfma(hhi, w2[1][2 * j + 1], a1);
            a2 = pkfma(hlo, w2[2][2 * j], a2); a2 = pkfma(hhi, w2[2][2 * j + 1], a2);
            a3 = pkfma(hlo, w2[3][2 * j], a3); a3 = pkfma(hhi, w2[3][2 * j + 1], a3);
        }
        float xb = xv2 + bb;
        float v0 = a0[0] + a0[1] + (p == 0 ? xb : 0.f);
        float v1 = a1[0] + a1[1] + (p == 1 ? xb : 0.f);
        float v2 = a2[0] + a2[1] + (p == 2 ? xb : 0.f);
        float v3 = a3[0] + a3[1] + (p == 3 ? xb : 0.f);
        v0 = quad_sum(v0); v1 = quad_sum(v1); v2 = quad_sum(v2); v3 = quad_sum(v3);

        float fi = fsig(v0), ff = fsig(v1), fg = ftanh(v2), fo = fsig(v3);
        c = ff * c + fi * fg;
        float hn = fo * ftanh(c);
        if (p == 0) {
            hbuf[(t + 1) & 1][hidx(u)] = hn;
            hs[((size_t)b << 13) + ((size_t)(t + 1) << 7) + u] = f2bf(hn);
        }
        __syncthreads();
        xv2 = xn;
    }
}

// ---------------- FC head: fw read once per block; A/B: NORMAL stores (was NT) ----------------
#define LDSW 260  // 256 + 4 pad dwords
__global__ __launch_bounds__(256) void fc_k(const unsigned short* __restrict__ hs,
                                            const unsigned short* __restrict__ fw,
                                            const float* __restrict__ fb,
                                            float* __restrict__ out) {
    int id = blockIdx.x;
    int bq = id / 125;   // 0..3
    int nb = id % 125;   // 0..124
    int n0 = nb * 256;
    int wave = threadIdx.x >> 6;
    int lane = threadIdx.x & 63;
    int l15 = lane & 15;
    int kg = lane >> 4;

    __shared__ __align__(16) float lds[64 * LDSW];

    // fw fragments: A[M = n = ns*16+l15][K = kt*32 + kg*8 + j], ns = wave*4+i
    bf16x8 a[4][4];
#pragma unroll
    for (int i = 0; i < 4; ++i) {
        const unsigned short* arow = fw + (size_t)(n0 + (wave * 4 + i) * 16 + l15) * HH + kg * 8;
#pragma unroll
        for (int kt = 0; kt < 4; ++kt) a[i][kt] = *(const bf16x8*)(arow + kt * 32);
    }

    float4 biasv = *(const float4*)(fb + n0 + lane * 4);

#pragma unroll 1
    for (int bi = 0; bi < 16; ++bi) {
        int b = bq * 16 + bi;

        // B fragments: row index = OUT row ot = ts*16+l15 (hs[b][ot] = h step ot-1; row0 = zeros)
        const unsigned short* ph = hs + ((size_t)b << 13);
        bf16x8 bfr[4][4];
#pragma unroll
        for (int ts = 0; ts < 4; ++ts) {
            const unsigned short* pr = ph + ((size_t)(ts * 16 + l15) << 7) + kg * 8;
#pragma unroll
            for (int kt = 0; kt < 4; ++kt) bfr[ts][kt] = *(const bf16x8*)(pr + kt * 32);
        }

#pragma unroll
        for (int i = 0; i < 4; ++i) {
            f32x4 ac0 = (f32x4){0.f, 0.f, 0.f, 0.f};
            f32x4 ac1 = (f32x4){0.f, 0.f, 0.f, 0.f};
            f32x4 ac2 = (f32x4){0.f, 0.f, 0.f, 0.f};
            f32x4 ac3 = (f32x4){0.f, 0.f, 0.f, 0.f};
#pragma unroll
            for (int kt = 0; kt < 4; ++kt) {
                ac0 = __builtin_amdgcn_mfma_f32_16x16x32_bf16(a[i][kt], bfr[0][kt], ac0, 0, 0, 0);
                ac1 = __builtin_amdgcn_mfma_f32_16x16x32_bf16(a[i][kt], bfr[1][kt], ac1, 0, 0, 0);
                ac2 = __builtin_amdgcn_mfma_f32_16x16x32_bf16(a[i][kt], bfr[2][kt], ac2, 0, 0, 0);
                ac3 = __builtin_amdgcn_mfma_f32_16x16x32_bf16(a[i][kt], bfr[3][kt], ac3, 0, 0, 0);
            }
            // D: lane l15 -> out row (N), regs j -> n offset (wave*4+i)*16 + kg*4 + j (M)
            int nc = (wave * 4 + i) * 16 + kg * 4;
#define DUMP(ts, accv)                                                         \
            *(f32x4*)(&lds[(ts * 16 + l15) * LDSW + nc]) = accv;
            DUMP(0, ac0) DUMP(1, ac1) DUMP(2, ac2) DUMP(3, ac3)
#undef DUMP
        }
        __syncthreads();

        // store: wave w -> rows ot = 16w .. 16w+15, 1KB contiguous each
        size_t outb = (size_t)b * TTOT * VOUT + n0 + lane * 4;
#pragma unroll
        for (int r = 0; r < 16; ++r) {
            int ot = wave * 16 + r;
            f32x4 v;
            if (ot == 0) {
                v = (f32x4){0.f, 0.f, 0.f, 0.f};
            } else {
                f32x4 s = *(const f32x4*)(&lds[ot * LDSW + lane * 4]);
                v[0] = s[0] + biasv.x; v[1] = s[1] + biasv.y;
                v[2] = s[2] + biasv.z; v[3] = s[3] + biasv.w;
            }
            *(f32x4*)(out + outb + (size_t)ot * VOUT) = v;
        }
        __syncthreads();
    }
}

extern "C" void kernel_launch(void* const* d_in, const int* in_sizes, int n_in,
                              void* d_out, int out_size, void* d_ws, size_t ws_size,
                              hipStream_t stream) {
    const int* src = (const int*)d_in[0];
    const int* tgt = (const int*)d_in[1];
    const float* enc_emb = (const float*)d_in[2];
    const float* dec_emb = (const float*)d_in[3];
    const float* enc_Wih = (const float*)d_in[4];
    const float* enc_Whh = (const float*)d_in[5];
    const float* enc_bih = (const float*)d_in[6];
    const float* enc_bhh = (const float*)d_in[7];
    const float* dec_Wih = (const float*)d_in[8];
    const float* dec_Whh = (const float*)d_in[9];
    const float* dec_bih = (const float*)d_in[10];
    const float* dec_bhh = (const float*)d_in[11];
    const float* fc_W = (const float*)d_in[12];
    const float* fc_b = (const float*)d_in[13];
    float* out = (float*)d_out;
    char* ws = (char*)d_ws;

    // workspace layout (bytes)
    float* table = (float*)(ws + 0);                        // 256*512*4      = 524288
    unsigned short* hs = (unsigned short*)(ws + 524288);    // 64*64*128*2    = 1048576 ([b][t][u])
    unsigned short* fwb = (unsigned short*)(ws + 1572864);  // 32000*128*2    = 8192000
    float* xgd = (float*)(ws + 9764864);                    // 63*64*512*4    = 8257536
    // total 18022400 bytes

    prep_k<<<256 + 252, 512, 0, stream>>>(enc_emb, enc_Wih, enc_bih, table,
                                          tgt, dec_emb, dec_Wih, dec_bih, xgd);
    lstm_k<<<BB + 512, 512, 0, stream>>>(table, src, enc_Whh, enc_bhh, xgd,
                                         dec_Whh, dec_bhh, hs, fc_W, fwb);
    fc_k<<<4 * 125, 256, 0, stream>>>(hs, fwb, fc_b, out);
}

// Round 12
// 240.687 us; speedup vs baseline: 1.0519x; 1.0519x over previous
//
#include <hip/hip_runtime.h>
#include <hip/hip_bf16.h>
#include <stddef.h>

// Problem dims
#define BB 64
#define TTOT 64
#define EE 64
#define HH 128
#define G4 512          // 4*H
#define VIN 256
#define VOUT 32000

typedef __attribute__((ext_vector_type(8))) short bf16x8;
typedef __attribute__((ext_vector_type(4))) float f32x4;
typedef __attribute__((ext_vector_type(2))) float f32x2;

__device__ __forceinline__ unsigned short f2bf(float x) {
    unsigned int u = __float_as_uint(x);
    unsigned int r = (u + 0x7fffu + ((u >> 16) & 1u)) >> 16;
    return (unsigned short)r;
}

__device__ __forceinline__ float fsig(float x) {
    return 1.f / (1.f + __expf(-x));
}
__device__ __forceinline__ float ftanh(float x) {
    return 1.f - 2.f / (__expf(2.f * x) + 1.f);
}

// packed fp32 FMA: d.lo = a.lo*b.lo + d.lo ; d.hi = a.hi*b.hi + d.hi
__device__ __forceinline__ f32x2 pkfma(f32x2 a, f32x2 b, f32x2 d) {
    asm("v_pk_fma_f32 %0, %1, %2, %0" : "+v"(d) : "v"(a), "v"(b));
    return d;
}

// quad (4-lane) butterfly sum via DPP quad_perm — pure VALU, no DS ops.
__device__ __forceinline__ float quad_sum(float v) {
    v += __int_as_float(__builtin_amdgcn_mov_dpp(__float_as_int(v), 0xB1, 0xF, 0xF, true));  // xor 1
    v += __int_as_float(__builtin_amdgcn_mov_dpp(__float_as_int(v), 0x4E, 0xF, 0xF, true));  // xor 2
    return v;
}

// LDS h layout: pad 8 dwords every 32 so the four 32-float quarters start in
// different bank groups: idx(u) = u + (u>>5)*8  (quarter p base = p*40 dwords)
__device__ __forceinline__ int hidx(int u) { return u + (u >> 5) * 8; }
#define HPAD 152

// ---------------- prep kernel: enc_table (blocks 0..255) + xg_dec (blocks 256..507) ----------------
__global__ __launch_bounds__(512) void prep_k(const float* __restrict__ enc_emb,
                                              const float* __restrict__ eWih,
                                              const float* __restrict__ ebih,
                                              float* __restrict__ table,
                                              const int* __restrict__ tgt,
                                              const float* __restrict__ dec_emb,
                                              const float* __restrict__ dWih,
                                              const float* __restrict__ dbih,
                                              float* __restrict__ xg) {
    __shared__ __align__(16) float x[16][EE];
    int g = threadIdx.x;
    if (blockIdx.x < 256) {
        int v = blockIdx.x;
        if (g < EE) x[0][g] = (v == 0) ? 0.f : enc_emb[(size_t)v * EE + g];
        __syncthreads();
        float acc = ebih[g];
        const float* wr = eWih + (size_t)g * EE;
#pragma unroll
        for (int e = 0; e < EE; e += 4) {
            float4 w4 = *(const float4*)(wr + e);
            float4 x4 = *(const float4*)(&x[0][e]);
            acc = fmaf(x4.x, w4.x, acc);
            acc = fmaf(x4.y, w4.y, acc);
            acc = fmaf(x4.z, w4.z, acc);
            acc = fmaf(x4.w, w4.w, acc);
        }
        table[(size_t)v * G4 + g] = acc;
    } else {
        int p0 = (blockIdx.x - 256) * 16;  // pair index = t*64 + b, t in [0,63)
        {
            int e = g & 63;
#pragma unroll
            for (int half = 0; half < 2; ++half) {
                int pr = (g >> 6) + half * 8;
                int pair = p0 + pr;
                int t = pair >> 6, b = pair & 63;
                int tok = tgt[b * TTOT + t];
                x[pr][e] = (tok == 0) ? 0.f : dec_emb[(size_t)tok * EE + e];
            }
        }
        __syncthreads();
        float bi = dbih[g];
        float acc[16];
#pragma unroll
        for (int pr = 0; pr < 16; ++pr) acc[pr] = bi;
        const float* wr = dWih + (size_t)g * EE;
#pragma unroll
        for (int e = 0; e < EE; e += 4) {
            float4 w4 = *(const float4*)(wr + e);
#pragma unroll
            for (int pr = 0; pr < 16; ++pr) {
                float4 x4 = *(const float4*)(&x[pr][e]);
                acc[pr] = fmaf(x4.x, w4.x, acc[pr]);
                acc[pr] = fmaf(x4.y, w4.y, acc[pr]);
                acc[pr] = fmaf(x4.z, w4.z, acc[pr]);
                acc[pr] = fmaf(x4.w, w4.w, acc[pr]);
            }
        }
#pragma unroll
        for (int pr = 0; pr < 16; ++pr)
            xg[(size_t)(p0 + pr) * G4 + g] = acc[pr];
    }
}

// ---------------- fused encoder+decoder LSTM (blocks 0..63) + fc_W bf16 convert (blocks 64..575) ----------------
__global__ __launch_bounds__(512) void lstm_k(const float* __restrict__ table,
                                              const int* __restrict__ src,
                                              const float* __restrict__ eWhh,
                                              const float* __restrict__ ebhh,
                                              const float* __restrict__ xg,
                                              const float* __restrict__ dWhh,
                                              const float* __restrict__ dbhh,
                                              unsigned short* __restrict__ hs,
                                              const float* __restrict__ fcW,
                                              unsigned short* __restrict__ fwb) {
    if (blockIdx.x >= BB) {
        // fc_W fp32 -> bf16, grid-stride over float4 items
        int i0 = (blockIdx.x - BB) * 512 + threadIdx.x;
        const int n4 = VOUT * HH / 4;       // 1,024,000
        const int stride = 512 * 512;       // 262,144
#pragma unroll 1
        for (int i = i0; i < n4; i += stride) {
            float4 v = *(const float4*)(fcW + (size_t)i * 4);
            ushort4 o;
            o.x = f2bf(v.x); o.y = f2bf(v.y); o.z = f2bf(v.z); o.w = f2bf(v.w);
            *(ushort4*)(fwb + (size_t)i * 4) = o;
        }
        return;
    }

    int b = blockIdx.x;
    int tid = threadIdx.x;
    int u = tid >> 2, p = tid & 3;
    __shared__ __align__(16) float hbuf[2][HPAD];
    __shared__ int toks[TTOT];

    // encoder weights as f32x2 pairs: w2[q][j] = Whh[q*128+u][p*32 + 2j .. 2j+1]
    f32x2 w2[4][16];
#pragma unroll
    for (int q = 0; q < 4; ++q) {
        const float* wr = eWhh + (size_t)(q * HH + u) * HH + p * 32;
#pragma unroll
        for (int kk = 0; kk < 32; kk += 4) {
            float4 t4 = *(const float4*)(wr + kk);
            w2[q][kk >> 1] = (f32x2){t4.x, t4.y};
            w2[q][(kk >> 1) + 1] = (f32x2){t4.z, t4.w};
        }
    }
    if (tid < TTOT) toks[tid] = src[b * TTOT + tid];
    if (p == 0) {
        hbuf[0][hidx(u)] = 0.f;
        hs[((size_t)b << 13) + u] = 0;  // out-row 0 operand = zeros
    }
    float bb = ebhh[p * HH + u];
    float c = 0.f;
    __syncthreads();

    float xv = table[(size_t)toks[0] * G4 + p * HH + u];

    // ---- encoder: 64 steps ----
#pragma unroll 1
    for (int t = 0; t < TTOT; ++t) {
        float xn = (t + 1 < TTOT) ? table[(size_t)toks[t + 1] * G4 + p * HH + u] : 0.f;
        const float* hq = &hbuf[t & 1][p * 40];
        float4 h4[8];
#pragma unroll
        for (int j = 0; j < 8; ++j) h4[j] = *(const float4*)(hq + j * 4);

        f32x2 a0 = (f32x2){0.f, 0.f}, a1 = a0, a2 = a0, a3 = a0;
#pragma unroll
        for (int j = 0; j < 8; ++j) {
            float4 h = h4[j];
            f32x2 hlo = (f32x2){h.x, h.y};
            f32x2 hhi = (f32x2){h.z, h.w};
            a0 = pkfma(hlo, w2[0][2 * j], a0); a0 = pkfma(hhi, w2[0][2 * j + 1], a0);
            a1 = pkfma(hlo, w2[1][2 * j], a1); a1 = pkfma(hhi, w2[1][2 * j + 1], a1);
            a2 = pkfma(hlo, w2[2][2 * j], a2); a2 = pkfma(hhi, w2[2][2 * j + 1], a2);
            a3 = pkfma(hlo, w2[3][2 * j], a3); a3 = pkfma(hhi, w2[3][2 * j + 1], a3);
        }
        float xb = xv + bb;
        float v0 = a0[0] + a0[1] + (p == 0 ? xb : 0.f);
        float v1 = a1[0] + a1[1] + (p == 1 ? xb : 0.f);
        float v2 = a2[0] + a2[1] + (p == 2 ? xb : 0.f);
        float v3 = a3[0] + a3[1] + (p == 3 ? xb : 0.f);
        v0 = quad_sum(v0); v1 = quad_sum(v1); v2 = quad_sum(v2); v3 = quad_sum(v3);

        float fi = fsig(v0), ff = fsig(v1), fg = ftanh(v2), fo = fsig(v3);
        c = ff * c + fi * fg;
        float hn = fo * ftanh(c);
        if (p == 0) hbuf[(t + 1) & 1][hidx(u)] = hn;
        __syncthreads();
        xv = xn;
    }

    // ---- switch to decoder weights; h/c stay ----
#pragma unroll
    for (int q = 0; q < 4; ++q) {
        const float* wr = dWhh + (size_t)(q * HH + u) * HH + p * 32;
#pragma unroll
        for (int kk = 0; kk < 32; kk += 4) {
            float4 t4 = *(const float4*)(wr + kk);
            w2[q][kk >> 1] = (f32x2){t4.x, t4.y};
            w2[q][(kk >> 1) + 1] = (f32x2){t4.z, t4.w};
        }
    }
    bb = dbhh[p * HH + u];
    float xv2 = xg[(size_t)b * G4 + p * HH + u];  // t=0 (pair = 0*64 + b)

    // ---- decoder: 63 steps; enc ended with h in hbuf[0] ----
#pragma unroll 1
    for (int t = 0; t < TTOT - 1; ++t) {
        float xn = (t + 1 < TTOT - 1) ? xg[((size_t)(t + 1) * BB + b) * G4 + p * HH + u] : 0.f;
        const float* hq = &hbuf[t & 1][p * 40];
        float4 h4[8];
#pragma unroll
        for (int j = 0; j < 8; ++j) h4[j] = *(const float4*)(hq + j * 4);

        f32x2 a0 = (f32x2){0.f, 0.f}, a1 = a0, a2 = a0, a3 = a0;
#pragma unroll
        for (int j = 0; j < 8; ++j) {
            float4 h = h4[j];
            f32x2 hlo = (f32x2){h.x, h.y};
            f32x2 hhi = (f32x2){h.z, h.w};
            a0 = pkfma(hlo, w2[0][2 * j], a0); a0 = pkfma(hhi, w2[0][2 * j + 1], a0);
            a1 = pkfma(hlo, w2[1][2 * j], a1); a1 = pkfma(hhi, w2[1][2 * j + 1], a1);
            a2 = pkfma(hlo, w2[2][2 * j], a2); a2 = pkfma(hhi, w2[2][2 * j + 1], a2);
            a3 = pkfma(hlo, w2[3][2 * j], a3); a3 = pkfma(hhi, w2[3][2 * j + 1], a3);
        }
        float xb = xv2 + bb;
        float v0 = a0[0] + a0[1] + (p == 0 ? xb : 0.f);
        float v1 = a1[0] + a1[1] + (p == 1 ? xb : 0.f);
        float v2 = a2[0] + a2[1] + (p == 2 ? xb : 0.f);
        float v3 = a3[0] + a3[1] + (p == 3 ? xb : 0.f);
        v0 = quad_sum(v0); v1 = quad_sum(v1); v2 = quad_sum(v2); v3 = quad_sum(v3);

        float fi = fsig(v0), ff = fsig(v1), fg = ftanh(v2), fo = fsig(v3);
        c = ff * c + fi * fg;
        float hn = fo * ftanh(c);
        if (p == 0) {
            hbuf[(t + 1) & 1][hidx(u)] = hn;
            hs[((size_t)b << 13) + ((size_t)(t + 1) << 7) + u] = f2bf(hn);
        }
        __syncthreads();
        xv2 = xn;
    }
}

// ---------------- FC head: fw-once + double-buffered half-tile pipeline + NT stores ----------------
// block = (b-quarter bq, n-band of 256), bq-major grid (id = bq*125 + nb).
// fw fragments a[4][4] loaded once. 32 phases: phase = (bi, half of 32 rows).
// Each phase: gather next bfr -> NT-store current half (8x1KB/wave) -> MFMA+dump
// next half into the other LDS buffer -> one barrier. Stores overlap compute.
#define LDSW2 260  // 256 + 4 pad dwords
__global__ __launch_bounds__(256) void fc_k(const unsigned short* __restrict__ hs,
                                            const unsigned short* __restrict__ fw,
                                            const float* __restrict__ fb,
                                            float* __restrict__ out) {
    int id = blockIdx.x;
    int bq = id / 125;   // 0..3
    int nb = id % 125;   // 0..124
    int n0 = nb * 256;
    int wave = threadIdx.x >> 6;
    int lane = threadIdx.x & 63;
    int l15 = lane & 15;
    int kg = lane >> 4;

    __shared__ __align__(16) float lds[2][32 * LDSW2];

    // fw fragments: A[M = n = (wave*4+i)*16+l15][K = kt*32 + kg*8 + j]
    bf16x8 a[4][4];
#pragma unroll
    for (int i = 0; i < 4; ++i) {
        const unsigned short* arow = fw + (size_t)(n0 + (wave * 4 + i) * 16 + l15) * HH + kg * 8;
#pragma unroll
        for (int kt = 0; kt < 4; ++kt) a[i][kt] = *(const bf16x8*)(arow + kt * 32);
    }
    float4 biasv = *(const float4*)(fb + n0 + lane * 4);

    bf16x8 bfr[2][4];

    // GATHER(b, h): bfr[ts2][kt] = hs[b][h*32 + ts2*16 + l15][kt*32 + kg*8 ..]
#define GATHER(bv, hv)                                                            \
    {                                                                             \
        const unsigned short* ph_ = hs + ((size_t)(bv) << 13);                    \
        _Pragma("unroll")                                                         \
        for (int ts2 = 0; ts2 < 2; ++ts2) {                                       \
            const unsigned short* pr_ =                                           \
                ph_ + ((size_t)((hv) * 32 + ts2 * 16 + l15) << 7) + kg * 8;       \
            _Pragma("unroll")                                                     \
            for (int kt = 0; kt < 4; ++kt) bfr[ts2][kt] = *(const bf16x8*)(pr_ + kt * 32); \
        }                                                                         \
    }

    // COMPUTE_DUMP(buf): 4 n-subtiles x 2 t-subtiles -> lds[buf]
#define COMPUTE_DUMP(bufv)                                                        \
    {                                                                             \
        _Pragma("unroll")                                                         \
        for (int i = 0; i < 4; ++i) {                                             \
            _Pragma("unroll")                                                     \
            for (int ts2 = 0; ts2 < 2; ++ts2) {                                   \
                f32x4 acc = (f32x4){0.f, 0.f, 0.f, 0.f};                          \
                _Pragma("unroll")                                                 \
                for (int kt = 0; kt < 4; ++kt)                                    \
                    acc = __builtin_amdgcn_mfma_f32_16x16x32_bf16(a[i][kt], bfr[ts2][kt], acc, 0, 0, 0); \
                *(f32x4*)(&lds[bufv][(ts2 * 16 + l15) * LDSW2 + (wave * 4 + i) * 16 + kg * 4]) = acc; \
            }                                                                     \
        }                                                                         \
    }

    // STORE(b, h, buf): wave stores rows rloc = wave*8..wave*8+7 as 1KB NT rows
#define STORE(bv, hv, bufv)                                                       \
    {                                                                             \
        size_t outb_ = (size_t)(bv) * TTOT * VOUT + n0 + lane * 4;                \
        _Pragma("unroll")                                                         \
        for (int r = 0; r < 8; ++r) {                                             \
            int rloc = wave * 8 + r;                                              \
            int ot = (hv) * 32 + rloc;                                            \
            f32x4 v;                                                              \
            if (ot == 0) {                                                        \
                v = (f32x4){0.f, 0.f, 0.f, 0.f};                                  \
            } else {                                                              \
                f32x4 s = *(const f32x4*)(&lds[bufv][rloc * LDSW2 + lane * 4]);   \
                v[0] = s[0] + biasv.x; v[1] = s[1] + biasv.y;                     \
                v[2] = s[2] + biasv.z; v[3] = s[3] + biasv.w;                     \
            }                                                                     \
            __builtin_nontemporal_store(v, (f32x4*)(out + outb_ + (size_t)ot * VOUT)); \
        }                                                                         \
    }

    // prologue: phase 0 (bi=0, half=0) into buf 0
    GATHER(bq * 16, 0);
    COMPUTE_DUMP(0);
    __syncthreads();

#pragma unroll 1
    for (int ph = 0; ph < 32; ++ph) {
        int cb = bq * 16 + (ph >> 1);
        int chf = ph & 1;
        int nph = ph + 1;
        if (nph < 32) {
            int nbv = bq * 16 + (nph >> 1);
            int nhf = nph & 1;
            GATHER(nbv, nhf);             // issue loads early
            STORE(cb, chf, ph & 1);       // drain current half (overlaps gather latency)
            COMPUTE_DUMP(nph & 1);        // MFMA next half into other buffer
        } else {
            STORE(cb, chf, ph & 1);
        }
        __syncthreads();
    }
#undef GATHER
#undef COMPUTE_DUMP
#undef STORE
}

extern "C" void kernel_launch(void* const* d_in, const int* in_sizes, int n_in,
                              void* d_out, int out_size, void* d_ws, size_t ws_size,
                              hipStream_t stream) {
    const int* src = (const int*)d_in[0];
    const int* tgt = (const int*)d_in[1];
    const float* enc_emb = (const float*)d_in[2];
    const float* dec_emb = (const float*)d_in[3];
    const float* enc_Wih = (const float*)d_in[4];
    const float* enc_Whh = (const float*)d_in[5];
    const float* enc_bih = (const float*)d_in[6];
    const float* enc_bhh = (const float*)d_in[7];
    const float* dec_Wih = (const float*)d_in[8];
    const float* dec_Whh = (const float*)d_in[9];
    const float* dec_bih = (const float*)d_in[10];
    const float* dec_bhh = (const float*)d_in[11];
    const float* fc_W = (const float*)d_in[12];
    const float* fc_b = (const float*)d_in[13];
    float* out = (float*)d_out;
    char* ws = (char*)d_ws;

    // workspace layout (bytes)
    float* table = (float*)(ws + 0);                        // 256*512*4      = 524288
    unsigned short* hs = (unsigned short*)(ws + 524288);    // 64*64*128*2    = 1048576 ([b][t][u])
    unsigned short* fwb = (unsigned short*)(ws + 1572864);  // 32000*128*2    = 8192000
    float* xgd = (float*)(ws + 9764864);                    // 63*64*512*4    = 8257536
    // total 18022400 bytes

    prep_k<<<256 + 252, 512, 0, stream>>>(enc_emb, enc_Wih, enc_bih, table,
                                          tgt, dec_emb, dec_Wih, dec_bih, xgd);
    lstm_k<<<BB + 512, 512, 0, stream>>>(table, src, enc_Whh, enc_bhh, xgd,
                                         dec_Whh, dec_bhh, hs, fc_W, fwb);
    fc_k<<<4 * 125, 256, 0, stream>>>(hs, fwb, fc_b, out);
}